// Round 7
// baseline (192.996 us; speedup 1.0000x reference)
//
#include <hip/hip_runtime.h>
#include <hip/hip_cooperative_groups.h>

namespace cg = cooperative_groups;

typedef short short8 __attribute__((ext_vector_type(8)));
typedef float f32x4 __attribute__((ext_vector_type(4)));

#define NB 8
#define NC 64
#define NN 16384
#define NO 64
#define SQRT13 3.605551275463989f

// ws layout (floats):
// [0, 1024)     : partial (sum,sumsq) per (b,c)                 512*2
// [1024, 5120)  : pp[b][c][8] = {a, bsh, cp0..cp5}              512*8
// [5120, 7168)  : WtB bf16[o][c] row-major (4096 ushort = 8KB)

__device__ __forceinline__ unsigned short f2bf(float f) {
    unsigned int u = __builtin_bit_cast(unsigned int, f);
    u += 0x7fffu + ((u >> 16) & 1u);   // RNE
    return (unsigned short)(u >> 16);
}

__device__ __forceinline__ unsigned int pack_bf2(float lo, float hi) {
    return (unsigned int)f2bf(lo) | ((unsigned int)f2bf(hi) << 16);
}

__device__ __forceinline__ float tanh13(float x) {
    // sqrt(13)*tanh(x), exp-based; correct limits at +-inf
    float e = __expf(2.0f * x);
    float r = __builtin_amdgcn_rcpf(e + 1.0f);
    return fmaf(-2.0f * SQRT13, r, SQRT13);
}

__device__ __forceinline__ float yeval(float xv, float a, float bb,
                                       float c0, float c1, float c2,
                                       float c3, float c4, float c5) {
    float t = tanh13(fmaf(xv, a, bb));
    float gg = __expf(-0.5f * t * t);
    float p = c5;
    p = fmaf(p, t, c4);
    p = fmaf(p, t, c3);
    p = fmaf(p, t, c2);
    p = fmaf(p, t, c1);
    p = fmaf(p, t, c0);
    return gg * p;
}

// ---------------- phase bodies (shared between fused and fallback) ----------

__device__ __forceinline__ void phase1_stats(int bc, int tid,
        const float* __restrict__ x, float* __restrict__ part,
        const float* __restrict__ Wt, unsigned short* __restrict__ WtB,
        float (*red2)[4]) {
    const float* xp = x + (size_t)bc * NN;
    float s = 0.f, ss = 0.f;
    #pragma unroll
    for (int i = 0; i < 16; ++i) {
        float4 v = *(const float4*)(xp + i * 1024 + tid * 4);
        s  += v.x + v.y + v.z + v.w;
        ss += v.x * v.x + v.y * v.y + v.z * v.z + v.w * v.w;
    }
    for (int off = 32; off; off >>= 1) {
        s  += __shfl_down(s, off);
        ss += __shfl_down(ss, off);
    }
    int lane = tid & 63, wid = tid >> 6;
    if (lane == 0) { red2[0][wid] = s; red2[1][wid] = ss; }
    __syncthreads();
    if (tid == 0) {
        part[bc * 2 + 0] = red2[0][0] + red2[0][1] + red2[0][2] + red2[0][3];
        part[bc * 2 + 1] = red2[1][0] + red2[1][1] + red2[1][2] + red2[1][3];
    }
    if (bc == 0)
        for (int i = tid; i < 4096; i += 256) WtB[i] = f2bf(Wt[i]);
}

__device__ __forceinline__ void phase2_cost(int bc, int tid,
        const float* __restrict__ x, const float* __restrict__ part,
        const float* __restrict__ gamma, const float* __restrict__ beta,
        float* __restrict__ pp, float (*red6)[4]) {
    int c = bc & 63;
    float s = 0.f, ss = 0.f;
    #pragma unroll
    for (int bb = 0; bb < NB; ++bb) {
        s  += part[(bb * NC + c) * 2 + 0];
        ss += part[(bb * NC + c) * 2 + 1];
    }
    const float inv = 1.0f / (float)(NB * NN);
    float mean = s * inv;
    float var  = ss * inv - mean * mean;
    float istd = 1.0f / sqrtf(var + 1e-5f);
    float a   = gamma[c] * istd;
    float bsh = beta[c] - mean * a;

    const float* xp = x + (size_t)bc * NN;
    float m[6] = {0.f, 0.f, 0.f, 0.f, 0.f, 0.f};
    #pragma unroll 4
    for (int i = 0; i < 16; ++i) {
        float4 v = *(const float4*)(xp + i * 1024 + tid * 4);
        float xs[4] = {v.x, v.y, v.z, v.w};
        #pragma unroll
        for (int j = 0; j < 4; ++j) {
            float xn = fmaf(xs[j], a, bsh);
            float t  = tanh13(xn);
            float g  = __expf(-0.5f * t * t);
            float u  = g * xn;
            m[0] += u;
            u *= t; m[1] += u;
            u *= t; m[2] += u;
            u *= t; m[3] += u;
            u *= t; m[4] += u;
            u *= t; m[5] += u;
        }
    }
    int lane = tid & 63, wid = tid >> 6;
    #pragma unroll
    for (int k = 0; k < 6; ++k) {
        float v = m[k];
        for (int off = 32; off; off >>= 1) v += __shfl_down(v, off);
        if (lane == 0) red6[k][wid] = v;
    }
    __syncthreads();
    if (tid == 0) {
        float M[6];
        #pragma unroll
        for (int k = 0; k < 6; ++k)
            M[k] = red6[k][0] + red6[k][1] + red6[k][2] + red6[k][3];

        // Hermite coeff matrix h[k][j]: psi_k = g * sum_j h[k][j] t^j
        float h[6][6];
        #pragma unroll
        for (int k = 0; k < 6; ++k)
            #pragma unroll
            for (int j = 0; j < 6; ++j) h[k][j] = 0.f;
        h[0][0] = 0.7511255444649425f;
        h[1][1] = 1.0622519320271969f;
        for (int k = 2; k < 6; ++k) {
            float s2 = sqrtf(2.0f / k), s1 = sqrtf((k - 1.0f) / k);
            for (int j = 5; j >= 0; --j) {
                float v = (j > 0) ? s2 * h[k - 1][j - 1] : 0.f;
                h[k][j] = v - s1 * h[k - 2][j];
            }
        }
        float cst[6], mx = -1e30f;
        #pragma unroll
        for (int k = 0; k < 6; ++k) {
            float v = 0.f;
            #pragma unroll
            for (int j = 0; j < 6; ++j) v += h[k][j] * M[j];
            cst[k] = v;
            mx = fmaxf(mx, v);
        }
        float sum = 0.f, w[6];
        #pragma unroll
        for (int k = 0; k < 6; ++k) { w[k] = expf(cst[k] - mx); sum += w[k]; }
        float r = 1.0f / sum;
        float* P = pp + (size_t)bc * 8;
        P[0] = a; P[1] = bsh;
        #pragma unroll
        for (int j = 0; j < 6; ++j) {
            float v = 0.f;
            #pragma unroll
            for (int k = 0; k < 6; ++k) v += w[k] * r * h[k][j];
            P[2 + j] = v;
        }
    }
}

__device__ __forceinline__ void phase3_out(int bc, int tid,
        const float* __restrict__ x, const unsigned short* __restrict__ WtB,
        const float* __restrict__ bias, const float* __restrict__ pp,
        float* __restrict__ out, float* ppl) {
    int w    = tid >> 6;
    int l    = tid & 63;
    int grp  = l >> 4;
    int ln   = l & 15;
    int b    = bc >> 6;
    int tile = bc & 63;

    #pragma unroll
    for (int i0 = 0; i0 < 2; ++i0) {
        int i = i0 * 256 + tid;
        ppl[(i & 7) * 64 + (i >> 3)] = pp[(size_t)b * 512 + i];
    }
    __syncthreads();

    // A fragments: Wt[o][c] bf16, a[j] = A[mo*16+ln][kk*32+grp*8+j]
    short8 af[2][4];
    #pragma unroll
    for (int kk = 0; kk < 2; ++kk)
        #pragma unroll
        for (int mo = 0; mo < 4; ++mo)
            af[kk][mo] = *reinterpret_cast<const short8*>(
                WtB + (mo * 16 + ln) * 64 + kk * 32 + grp * 8);

    f32x4 acc[4][4];
    #pragma unroll
    for (int mo = 0; mo < 4; ++mo)
        #pragma unroll
        for (int nd = 0; nd < 4; ++nd)
            acc[mo][nd] = (f32x4){0.f, 0.f, 0.f, 0.f};

    const float* xb = x + (size_t)b * NC * NN + tile * 256 + w * 64 + ln;

    #pragma unroll
    for (int kk = 0; kk < 2; ++kk) {
        unsigned int bu[4][4];  // [nd][q]
        #pragma unroll
        for (int q = 0; q < 4; ++q) {
            int c0 = kk * 32 + grp * 8 + 2 * q;
            float A0 = ppl[c0],       A1 = ppl[c0 + 1];
            float B0 = ppl[64 + c0],  B1 = ppl[64 + c0 + 1];
            float p00 = ppl[128 + c0], p01 = ppl[192 + c0], p02 = ppl[256 + c0];
            float p03 = ppl[320 + c0], p04 = ppl[384 + c0], p05 = ppl[448 + c0];
            float p10 = ppl[129 + c0], p11 = ppl[193 + c0], p12 = ppl[257 + c0];
            float p13 = ppl[321 + c0], p14 = ppl[385 + c0], p15 = ppl[449 + c0];
            const float* xc0 = xb + (size_t)c0 * NN;
            const float* xc1 = xc0 + NN;
            #pragma unroll
            for (int nd = 0; nd < 4; ++nd) {
                float y0 = yeval(xc0[nd * 16], A0, B0, p00, p01, p02, p03, p04, p05);
                float y1 = yeval(xc1[nd * 16], A1, B1, p10, p11, p12, p13, p14, p15);
                bu[nd][q] = pack_bf2(y0, y1);
            }
        }
        #pragma unroll
        for (int nd = 0; nd < 4; ++nd) {
            union { unsigned int u[4]; short8 s; } U;
            U.u[0] = bu[nd][0]; U.u[1] = bu[nd][1];
            U.u[2] = bu[nd][2]; U.u[3] = bu[nd][3];
            #pragma unroll
            for (int mo = 0; mo < 4; ++mo)
                acc[mo][nd] = __builtin_amdgcn_mfma_f32_16x16x32_bf16(
                    af[kk][mo], U.s, acc[mo][nd], 0, 0, 0);
        }
    }

    // epilogue: C/D layout col=lane&15, row=(lane>>4)*4+reg (m89-verified)
    float* ob = out + (size_t)b * NO * NN + tile * 256 + w * 64 + ln;
    #pragma unroll
    for (int mo = 0; mo < 4; ++mo) {
        #pragma unroll
        for (int nd = 0; nd < 4; ++nd) {
            f32x4 v = acc[mo][nd];
            #pragma unroll
            for (int r = 0; r < 4; ++r) {
                int o = mo * 16 + grp * 4 + r;
                ob[(size_t)o * NN + nd * 16] = v[r] + bias[o];
            }
        }
    }
}

// ---------------- kernels ---------------------------------------------------

__global__ __launch_bounds__(256, 2) void k_fused(
    const float* __restrict__ x, const float* __restrict__ gamma,
    const float* __restrict__ beta, const float* __restrict__ Wt,
    const float* __restrict__ bias, float* __restrict__ part,
    float* __restrict__ pp, unsigned short* __restrict__ WtB,
    float* __restrict__ out) {
    cg::grid_group grid = cg::this_grid();
    __shared__ float red2[2][4];
    __shared__ float red6[6][4];
    __shared__ float ppl[512];
    int bc = blockIdx.x, tid = threadIdx.x;

    phase1_stats(bc, tid, x, part, Wt, WtB, red2);
    __threadfence();
    grid.sync();
    phase2_cost(bc, tid, x, part, gamma, beta, pp, red6);
    __threadfence();
    grid.sync();
    phase3_out(bc, tid, x, WtB, bias, pp, out, ppl);
}

__global__ __launch_bounds__(256) void k_stats(const float* __restrict__ x,
                                               float* __restrict__ part,
                                               const float* __restrict__ Wt,
                                               unsigned short* __restrict__ WtB) {
    __shared__ float red2[2][4];
    phase1_stats(blockIdx.x, threadIdx.x, x, part, Wt, WtB, red2);
}

__global__ __launch_bounds__(256) void k_cost(const float* __restrict__ x,
                                              const float* __restrict__ part,
                                              const float* __restrict__ gamma,
                                              const float* __restrict__ beta,
                                              float* __restrict__ pp) {
    __shared__ float red6[6][4];
    phase2_cost(blockIdx.x, threadIdx.x, x, part, gamma, beta, pp, red6);
}

__global__ __launch_bounds__(256) void k_out(const float* __restrict__ x,
                                             const unsigned short* __restrict__ WtB,
                                             const float* __restrict__ bias,
                                             const float* __restrict__ pp,
                                             float* __restrict__ out) {
    __shared__ float ppl[512];
    phase3_out(blockIdx.x, threadIdx.x, x, WtB, bias, pp, out, ppl);
}

extern "C" void kernel_launch(void* const* d_in, const int* in_sizes, int n_in,
                              void* d_out, int out_size, void* d_ws, size_t ws_size,
                              hipStream_t stream) {
    const float* x     = (const float*)d_in[0];
    const float* gamma = (const float*)d_in[1];
    const float* beta  = (const float*)d_in[2];
    const float* Wt    = (const float*)d_in[3];
    const float* bias  = (const float*)d_in[4];
    float* out = (float*)d_out;
    float* ws  = (float*)d_ws;

    float* part = ws;                                    // 1024 floats
    float* pp   = ws + 1024;                             // 4096 floats
    unsigned short* WtB = (unsigned short*)(ws + 5120);  // 4096 ushorts

    void* args[] = {(void*)&x, (void*)&gamma, (void*)&beta, (void*)&Wt,
                    (void*)&bias, (void*)&part, (void*)&pp, (void*)&WtB,
                    (void*)&out};
    hipError_t err = hipLaunchCooperativeKernel((const void*)k_fused,
                                                dim3(NB * NC), dim3(256),
                                                args, 0, stream);
    if (err != hipSuccess) {
        (void)hipGetLastError();  // clear sticky error, fall back to 3 kernels
        k_stats<<<dim3(NB * NC), dim3(256), 0, stream>>>(x, part, Wt, WtB);
        k_cost<<<dim3(NB * NC), dim3(256), 0, stream>>>(x, part, gamma, beta, pp);
        k_out<<<dim3(NB * NC), dim3(256), 0, stream>>>(x, WtB, bias, pp, out);
    }
}

// Round 8
// 39.165 us; speedup vs baseline: 4.9278x; 4.9278x over previous
//
#include <hip/hip_runtime.h>

typedef short short8 __attribute__((ext_vector_type(8)));
typedef float f32x4 __attribute__((ext_vector_type(4)));

#define NB 8
#define NC 64
#define NN 16384
#define NO 64
#define SQRT13 3.605551275463989f

// ws layout (floats):
// [0, 2048)     : partial (sum,sumsq) per half-row               1024*2
// [2048, 6144)  : pp[b][c][8] = {a, bsh, cp0..cp5}               512*8
// [6144, 8192)  : WtB bf16[o][c] row-major (4096 ushort = 8KB)

__device__ __forceinline__ unsigned short f2bf(float f) {
    unsigned int u = __builtin_bit_cast(unsigned int, f);
    u += 0x7fffu + ((u >> 16) & 1u);   // RNE
    return (unsigned short)(u >> 16);
}

__device__ __forceinline__ unsigned int pack_bf2(float lo, float hi) {
    return (unsigned int)f2bf(lo) | ((unsigned int)f2bf(hi) << 16);
}

__device__ __forceinline__ float tanh13(float x) {
    // sqrt(13)*tanh(x), exp-based; correct limits at +-inf
    float e = __expf(2.0f * x);
    float r = __builtin_amdgcn_rcpf(e + 1.0f);
    return fmaf(-2.0f * SQRT13, r, SQRT13);
}

__device__ __forceinline__ float yeval(float xv, float a, float bb,
                                       float c0, float c1, float c2,
                                       float c3, float c4, float c5) {
    float t = tanh13(fmaf(xv, a, bb));
    float gg = __expf(-0.5f * t * t);
    float p = c5;
    p = fmaf(p, t, c4);
    p = fmaf(p, t, c3);
    p = fmaf(p, t, c2);
    p = fmaf(p, t, c1);
    p = fmaf(p, t, c0);
    return gg * p;
}

// 1024 blocks, each reduces half of one (b,c) row -> 4 blocks/CU for latency hiding
__global__ __launch_bounds__(256) void k_stats(const float* __restrict__ x,
                                               float* __restrict__ part,
                                               const float* __restrict__ Wt,
                                               unsigned short* __restrict__ WtB) {
    int blk = blockIdx.x;                       // 0..1023
    const float* xp = x + (size_t)(blk >> 1) * NN + (blk & 1) * 8192;
    int tid = threadIdx.x;
    float s = 0.f, ss = 0.f;
    #pragma unroll
    for (int i = 0; i < 8; ++i) {
        float4 v = *(const float4*)(xp + i * 1024 + tid * 4);
        s  += v.x + v.y + v.z + v.w;
        ss += v.x * v.x + v.y * v.y + v.z * v.z + v.w * v.w;
    }
    for (int off = 32; off; off >>= 1) {
        s  += __shfl_down(s, off);
        ss += __shfl_down(ss, off);
    }
    __shared__ float red[2][4];
    int lane = tid & 63, wid = tid >> 6;
    if (lane == 0) { red[0][wid] = s; red[1][wid] = ss; }
    __syncthreads();
    if (tid == 0) {
        part[blk * 2 + 0] = red[0][0] + red[0][1] + red[0][2] + red[0][3];
        part[blk * 2 + 1] = red[1][0] + red[1][1] + red[1][2] + red[1][3];
    }
    if (blk == 0)
        for (int i = tid; i < 4096; i += 256) WtB[i] = f2bf(Wt[i]);
}

// 512 blocks x 512 threads (16 waves/CU), one block per (b,c)
__global__ __launch_bounds__(512) void k_cost(const float* __restrict__ x,
                                              const float* __restrict__ part,
                                              const float* __restrict__ gamma,
                                              const float* __restrict__ beta,
                                              float* __restrict__ pp) {
    int bc = blockIdx.x;
    int c  = bc & 63;
    int tid = threadIdx.x;

    float s = 0.f, ss = 0.f;
    #pragma unroll
    for (int bb = 0; bb < NB; ++bb) {
        int base = ((bb * NC + c) << 1);        // two half-row partials
        s  += part[base * 2 + 0] + part[base * 2 + 2];
        ss += part[base * 2 + 1] + part[base * 2 + 3];
    }
    const float inv = 1.0f / (float)(NB * NN);
    float mean = s * inv;
    float var  = ss * inv - mean * mean;
    float istd = 1.0f / sqrtf(var + 1e-5f);
    float a   = gamma[c] * istd;
    float bsh = beta[c] - mean * a;

    const float* xp = x + (size_t)bc * NN;
    float m[6] = {0.f, 0.f, 0.f, 0.f, 0.f, 0.f};
    #pragma unroll 4
    for (int i = 0; i < 8; ++i) {
        float4 v = *(const float4*)(xp + i * 2048 + tid * 4);
        float xs[4] = {v.x, v.y, v.z, v.w};
        #pragma unroll
        for (int j = 0; j < 4; ++j) {
            float xn = fmaf(xs[j], a, bsh);
            float t  = tanh13(xn);
            float g  = __expf(-0.5f * t * t);
            float u  = g * xn;
            m[0] += u;
            u *= t; m[1] += u;
            u *= t; m[2] += u;
            u *= t; m[3] += u;
            u *= t; m[4] += u;
            u *= t; m[5] += u;
        }
    }
    __shared__ float red6[6][8];
    int lane = tid & 63, wid = tid >> 6;
    #pragma unroll
    for (int k = 0; k < 6; ++k) {
        float v = m[k];
        for (int off = 32; off; off >>= 1) v += __shfl_down(v, off);
        if (lane == 0) red6[k][wid] = v;
    }
    __syncthreads();
    if (tid == 0) {
        float M[6];
        #pragma unroll
        for (int k = 0; k < 6; ++k) {
            float v = 0.f;
            #pragma unroll
            for (int w = 0; w < 8; ++w) v += red6[k][w];
            M[k] = v;
        }

        // Hermite coeff matrix h[k][j]: psi_k = g * sum_j h[k][j] t^j
        float h[6][6];
        #pragma unroll
        for (int k = 0; k < 6; ++k)
            #pragma unroll
            for (int j = 0; j < 6; ++j) h[k][j] = 0.f;
        h[0][0] = 0.7511255444649425f;
        h[1][1] = 1.0622519320271969f;
        for (int k = 2; k < 6; ++k) {
            float s2 = sqrtf(2.0f / k), s1 = sqrtf((k - 1.0f) / k);
            for (int j = 5; j >= 0; --j) {
                float v = (j > 0) ? s2 * h[k - 1][j - 1] : 0.f;
                h[k][j] = v - s1 * h[k - 2][j];
            }
        }
        float cst[6], mx = -1e30f;
        #pragma unroll
        for (int k = 0; k < 6; ++k) {
            float v = 0.f;
            #pragma unroll
            for (int j = 0; j < 6; ++j) v += h[k][j] * M[j];
            cst[k] = v;
            mx = fmaxf(mx, v);
        }
        float sum = 0.f, w[6];
        #pragma unroll
        for (int k = 0; k < 6; ++k) { w[k] = expf(cst[k] - mx); sum += w[k]; }
        float r = 1.0f / sum;
        float* P = pp + (size_t)bc * 8;
        P[0] = a; P[1] = bsh;
        #pragma unroll
        for (int j = 0; j < 6; ++j) {
            float v = 0.f;
            #pragma unroll
            for (int k = 0; k < 6; ++k) v += w[k] * r * h[k][j];
            P[2 + j] = v;
        }
    }
}

__global__ __launch_bounds__(256) void k_out(const float* __restrict__ x,
                                             const unsigned short* __restrict__ WtB,
                                             const float* __restrict__ bias,
                                             const float* __restrict__ pp,
                                             float* __restrict__ out) {
    __shared__ float ppl[512];  // SoA: ppl[f*64 + c]
    int tid  = threadIdx.x;
    int w    = tid >> 6;
    int l    = tid & 63;
    int grp  = l >> 4;
    int ln   = l & 15;
    int b    = blockIdx.x >> 6;
    int tile = blockIdx.x & 63;

    #pragma unroll
    for (int i0 = 0; i0 < 2; ++i0) {
        int i = i0 * 256 + tid;
        ppl[(i & 7) * 64 + (i >> 3)] = pp[(size_t)b * 512 + i];
    }
    __syncthreads();

    // A fragments: Wt[o][c] bf16, a[j] = A[mo*16+ln][kk*32+grp*8+j]
    short8 af[2][4];
    #pragma unroll
    for (int kk = 0; kk < 2; ++kk)
        #pragma unroll
        for (int mo = 0; mo < 4; ++mo)
            af[kk][mo] = *reinterpret_cast<const short8*>(
                WtB + (mo * 16 + ln) * 64 + kk * 32 + grp * 8);

    // bias values this thread stores: o = mo*16 + grp*4 + r
    float4 bias4[4];
    #pragma unroll
    for (int mo = 0; mo < 4; ++mo)
        bias4[mo] = *(const float4*)(bias + mo * 16 + grp * 4);

    f32x4 acc[4][4];
    #pragma unroll
    for (int mo = 0; mo < 4; ++mo)
        #pragma unroll
        for (int nd = 0; nd < 4; ++nd)
            acc[mo][nd] = (f32x4){0.f, 0.f, 0.f, 0.f};

    const float* xb = x + (size_t)b * NC * NN + tile * 256 + w * 64 + ln;

    #pragma unroll
    for (int kk = 0; kk < 2; ++kk) {
        unsigned int bu[4][4];  // [nd][q]
        #pragma unroll
        for (int q = 0; q < 4; ++q) {
            int c0 = kk * 32 + grp * 8 + 2 * q;
            float A0 = ppl[c0],       A1 = ppl[c0 + 1];
            float B0 = ppl[64 + c0],  B1 = ppl[64 + c0 + 1];
            float p00 = ppl[128 + c0], p01 = ppl[192 + c0], p02 = ppl[256 + c0];
            float p03 = ppl[320 + c0], p04 = ppl[384 + c0], p05 = ppl[448 + c0];
            float p10 = ppl[129 + c0], p11 = ppl[193 + c0], p12 = ppl[257 + c0];
            float p13 = ppl[321 + c0], p14 = ppl[385 + c0], p15 = ppl[449 + c0];
            const float* xc0 = xb + (size_t)c0 * NN;
            const float* xc1 = xc0 + NN;
            #pragma unroll
            for (int nd = 0; nd < 4; ++nd) {
                float y0 = yeval(xc0[nd * 16], A0, B0, p00, p01, p02, p03, p04, p05);
                float y1 = yeval(xc1[nd * 16], A1, B1, p10, p11, p12, p13, p14, p15);
                bu[nd][q] = pack_bf2(y0, y1);
            }
        }
        #pragma unroll
        for (int nd = 0; nd < 4; ++nd) {
            union { unsigned int u[4]; short8 s; } U;
            U.u[0] = bu[nd][0]; U.u[1] = bu[nd][1];
            U.u[2] = bu[nd][2]; U.u[3] = bu[nd][3];
            #pragma unroll
            for (int mo = 0; mo < 4; ++mo)
                acc[mo][nd] = __builtin_amdgcn_mfma_f32_16x16x32_bf16(
                    af[kk][mo], U.s, acc[mo][nd], 0, 0, 0);
        }
    }

    // epilogue: C/D layout col=lane&15, row=(lane>>4)*4+reg (m89-verified)
    // streaming stores: out is write-once, keep it out of L2
    float* ob = out + (size_t)b * NO * NN + tile * 256 + w * 64 + ln;
    #pragma unroll
    for (int mo = 0; mo < 4; ++mo) {
        #pragma unroll
        for (int nd = 0; nd < 4; ++nd) {
            f32x4 v = acc[mo][nd];
            __builtin_nontemporal_store(v[0] + bias4[mo].x, &ob[(size_t)(mo * 16 + grp * 4 + 0) * NN + nd * 16]);
            __builtin_nontemporal_store(v[1] + bias4[mo].y, &ob[(size_t)(mo * 16 + grp * 4 + 1) * NN + nd * 16]);
            __builtin_nontemporal_store(v[2] + bias4[mo].z, &ob[(size_t)(mo * 16 + grp * 4 + 2) * NN + nd * 16]);
            __builtin_nontemporal_store(v[3] + bias4[mo].w, &ob[(size_t)(mo * 16 + grp * 4 + 3) * NN + nd * 16]);
        }
    }
}

extern "C" void kernel_launch(void* const* d_in, const int* in_sizes, int n_in,
                              void* d_out, int out_size, void* d_ws, size_t ws_size,
                              hipStream_t stream) {
    const float* x     = (const float*)d_in[0];
    const float* gamma = (const float*)d_in[1];
    const float* beta  = (const float*)d_in[2];
    const float* Wt    = (const float*)d_in[3];
    const float* bias  = (const float*)d_in[4];
    float* out = (float*)d_out;
    float* ws  = (float*)d_ws;

    float* part = ws;                                    // 2048 floats
    float* pp   = ws + 2048;                             // 4096 floats
    unsigned short* WtB = (unsigned short*)(ws + 6144);  // 4096 ushorts

    k_stats<<<dim3(2 * NB * NC), dim3(256), 0, stream>>>(x, part, Wt, WtB);
    k_cost<<<dim3(NB * NC), dim3(512), 0, stream>>>(x, part, gamma, beta, pp);
    k_out<<<dim3(NB * NC), dim3(256), 0, stream>>>(x, WtB, bias, pp, out);
}

// Round 9
// 35.748 us; speedup vs baseline: 5.3988x; 1.0956x over previous
//
#include <hip/hip_runtime.h>

typedef short short8 __attribute__((ext_vector_type(8)));
typedef float f32x4 __attribute__((ext_vector_type(4)));

#define NB 8
#define NC 64
#define NN 16384
#define NO 64
#define SQRT13 3.605551275463989f

// ws layout (floats):
// [0, 1024)     : partial (sum,sumsq) per (b,c)                 512*2
// [1024, 5120)  : pp[b][c][8] = {a, bsh, cp0..cp5}              512*8
// [5120, 7168)  : WtB bf16[o][c] row-major (4096 ushort = 8KB)

__device__ __forceinline__ unsigned short f2bf(float f) {
    unsigned int u = __builtin_bit_cast(unsigned int, f);
    u += 0x7fffu + ((u >> 16) & 1u);   // RNE
    return (unsigned short)(u >> 16);
}

__device__ __forceinline__ unsigned int pack_bf2(float lo, float hi) {
    return (unsigned int)f2bf(lo) | ((unsigned int)f2bf(hi) << 16);
}

__device__ __forceinline__ float tanh13(float x) {
    // sqrt(13)*tanh(x), exp-based; correct limits at +-inf
    float e = __expf(2.0f * x);
    float r = __builtin_amdgcn_rcpf(e + 1.0f);
    return fmaf(-2.0f * SQRT13, r, SQRT13);
}

__device__ __forceinline__ float yeval(float xv, float a, float bb,
                                       float c0, float c1, float c2,
                                       float c3, float c4, float c5) {
    float t = tanh13(fmaf(xv, a, bb));
    float gg = __expf(-0.5f * t * t);
    float p = c5;
    p = fmaf(p, t, c4);
    p = fmaf(p, t, c3);
    p = fmaf(p, t, c2);
    p = fmaf(p, t, c1);
    p = fmaf(p, t, c0);
    return gg * p;
}

__global__ __launch_bounds__(256) void k_stats(const float* __restrict__ x,
                                               float* __restrict__ part,
                                               const float* __restrict__ Wt,
                                               unsigned short* __restrict__ WtB) {
    int bc = blockIdx.x;
    const float* xp = x + (size_t)bc * NN;
    int tid = threadIdx.x;
    float s = 0.f, ss = 0.f;
    #pragma unroll
    for (int i = 0; i < 16; ++i) {
        float4 v = *(const float4*)(xp + i * 1024 + tid * 4);
        s  += v.x + v.y + v.z + v.w;
        ss += v.x * v.x + v.y * v.y + v.z * v.z + v.w * v.w;
    }
    for (int off = 32; off; off >>= 1) {
        s  += __shfl_down(s, off);
        ss += __shfl_down(ss, off);
    }
    __shared__ float red[2][4];
    int lane = tid & 63, wid = tid >> 6;
    if (lane == 0) { red[0][wid] = s; red[1][wid] = ss; }
    __syncthreads();
    if (tid == 0) {
        part[bc * 2 + 0] = red[0][0] + red[0][1] + red[0][2] + red[0][3];
        part[bc * 2 + 1] = red[1][0] + red[1][1] + red[1][2] + red[1][3];
    }
    if (bc == 0)
        for (int i = tid; i < 4096; i += 256) WtB[i] = f2bf(Wt[i]);
}

__global__ __launch_bounds__(256) void k_cost(const float* __restrict__ x,
                                              const float* __restrict__ part,
                                              const float* __restrict__ gamma,
                                              const float* __restrict__ beta,
                                              float* __restrict__ pp) {
    int bc = blockIdx.x;
    int c  = bc & 63;
    int tid = threadIdx.x;

    float s = 0.f, ss = 0.f;
    #pragma unroll
    for (int bb = 0; bb < NB; ++bb) {
        s  += part[(bb * NC + c) * 2 + 0];
        ss += part[(bb * NC + c) * 2 + 1];
    }
    const float inv = 1.0f / (float)(NB * NN);
    float mean = s * inv;
    float var  = ss * inv - mean * mean;
    float istd = 1.0f / sqrtf(var + 1e-5f);
    float a   = gamma[c] * istd;
    float bsh = beta[c] - mean * a;

    const float* xp = x + (size_t)bc * NN;
    float m[6] = {0.f, 0.f, 0.f, 0.f, 0.f, 0.f};

    // two half-tiles: load 8 float4 up-front (32 VGPR), then compute.
    // 8 outstanding loads/wave hides ~900cy HBM latency far better than 4.
    #pragma unroll
    for (int half = 0; half < 2; ++half) {
        float4 v[8];
        #pragma unroll
        for (int i = 0; i < 8; ++i)
            v[i] = *(const float4*)(xp + (half * 8 + i) * 1024 + tid * 4);
        #pragma unroll
        for (int i = 0; i < 8; ++i) {
            float xs[4] = {v[i].x, v[i].y, v[i].z, v[i].w};
            #pragma unroll
            for (int j = 0; j < 4; ++j) {
                float xn = fmaf(xs[j], a, bsh);
                float t  = tanh13(xn);
                float g  = __expf(-0.5f * t * t);
                float u  = g * xn;
                m[0] += u;
                u *= t; m[1] += u;
                u *= t; m[2] += u;
                u *= t; m[3] += u;
                u *= t; m[4] += u;
                u *= t; m[5] += u;
            }
        }
    }

    __shared__ float red6[6][4];
    int lane = tid & 63, wid = tid >> 6;
    #pragma unroll
    for (int k = 0; k < 6; ++k) {
        float v = m[k];
        for (int off = 32; off; off >>= 1) v += __shfl_down(v, off);
        if (lane == 0) red6[k][wid] = v;
    }
    __syncthreads();
    if (tid == 0) {
        float M[6];
        #pragma unroll
        for (int k = 0; k < 6; ++k)
            M[k] = red6[k][0] + red6[k][1] + red6[k][2] + red6[k][3];

        // Hermite coeff matrix h[k][j]: psi_k = g * sum_j h[k][j] t^j
        float h[6][6];
        #pragma unroll
        for (int k = 0; k < 6; ++k)
            #pragma unroll
            for (int j = 0; j < 6; ++j) h[k][j] = 0.f;
        h[0][0] = 0.7511255444649425f;
        h[1][1] = 1.0622519320271969f;
        for (int k = 2; k < 6; ++k) {
            float s2 = sqrtf(2.0f / k), s1 = sqrtf((k - 1.0f) / k);
            for (int j = 5; j >= 0; --j) {
                float v = (j > 0) ? s2 * h[k - 1][j - 1] : 0.f;
                h[k][j] = v - s1 * h[k - 2][j];
            }
        }
        float cst[6], mx = -1e30f;
        #pragma unroll
        for (int k = 0; k < 6; ++k) {
            float v = 0.f;
            #pragma unroll
            for (int j = 0; j < 6; ++j) v += h[k][j] * M[j];
            cst[k] = v;
            mx = fmaxf(mx, v);
        }
        float sum = 0.f, w[6];
        #pragma unroll
        for (int k = 0; k < 6; ++k) { w[k] = expf(cst[k] - mx); sum += w[k]; }
        float r = 1.0f / sum;
        float* P = pp + (size_t)bc * 8;
        P[0] = a; P[1] = bsh;
        #pragma unroll
        for (int j = 0; j < 6; ++j) {
            float v = 0.f;
            #pragma unroll
            for (int k = 0; k < 6; ++k) v += w[k] * r * h[k][j];
            P[2 + j] = v;
        }
    }
}

__global__ __launch_bounds__(256) void k_out(const float* __restrict__ x,
                                             const unsigned short* __restrict__ WtB,
                                             const float* __restrict__ bias,
                                             const float* __restrict__ pp,
                                             float* __restrict__ out) {
    __shared__ float ppl[512];  // SoA: ppl[f*64 + c]
    int tid  = threadIdx.x;
    int w    = tid >> 6;
    int l    = tid & 63;
    int grp  = l >> 4;
    int ln   = l & 15;
    int b    = blockIdx.x >> 6;
    int tile = blockIdx.x & 63;

    #pragma unroll
    for (int i0 = 0; i0 < 2; ++i0) {
        int i = i0 * 256 + tid;
        ppl[(i & 7) * 64 + (i >> 3)] = pp[(size_t)b * 512 + i];
    }
    __syncthreads();

    // A fragments: Wt[o][c] bf16, a[j] = A[mo*16+ln][kk*32+grp*8+j]
    short8 af[2][4];
    #pragma unroll
    for (int kk = 0; kk < 2; ++kk)
        #pragma unroll
        for (int mo = 0; mo < 4; ++mo)
            af[kk][mo] = *reinterpret_cast<const short8*>(
                WtB + (mo * 16 + ln) * 64 + kk * 32 + grp * 8);

    // bias values this thread stores: o = mo*16 + grp*4 + r
    float4 bias4[4];
    #pragma unroll
    for (int mo = 0; mo < 4; ++mo)
        bias4[mo] = *(const float4*)(bias + mo * 16 + grp * 4);

    f32x4 acc[4][4];
    #pragma unroll
    for (int mo = 0; mo < 4; ++mo)
        #pragma unroll
        for (int nd = 0; nd < 4; ++nd)
            acc[mo][nd] = (f32x4){0.f, 0.f, 0.f, 0.f};

    const float* xb = x + (size_t)b * NC * NN + tile * 256 + w * 64 + ln;

    #pragma unroll
    for (int kk = 0; kk < 2; ++kk) {
        unsigned int bu[4][4];  // [nd][q]
        #pragma unroll
        for (int q = 0; q < 4; ++q) {
            int c0 = kk * 32 + grp * 8 + 2 * q;
            float A0 = ppl[c0],       A1 = ppl[c0 + 1];
            float B0 = ppl[64 + c0],  B1 = ppl[64 + c0 + 1];
            float p00 = ppl[128 + c0], p01 = ppl[192 + c0], p02 = ppl[256 + c0];
            float p03 = ppl[320 + c0], p04 = ppl[384 + c0], p05 = ppl[448 + c0];
            float p10 = ppl[129 + c0], p11 = ppl[193 + c0], p12 = ppl[257 + c0];
            float p13 = ppl[321 + c0], p14 = ppl[385 + c0], p15 = ppl[449 + c0];
            const float* xc0 = xb + (size_t)c0 * NN;
            const float* xc1 = xc0 + NN;
            #pragma unroll
            for (int nd = 0; nd < 4; ++nd) {
                float y0 = yeval(xc0[nd * 16], A0, B0, p00, p01, p02, p03, p04, p05);
                float y1 = yeval(xc1[nd * 16], A1, B1, p10, p11, p12, p13, p14, p15);
                bu[nd][q] = pack_bf2(y0, y1);
            }
        }
        #pragma unroll
        for (int nd = 0; nd < 4; ++nd) {
            union { unsigned int u[4]; short8 s; } U;
            U.u[0] = bu[nd][0]; U.u[1] = bu[nd][1];
            U.u[2] = bu[nd][2]; U.u[3] = bu[nd][3];
            #pragma unroll
            for (int mo = 0; mo < 4; ++mo)
                acc[mo][nd] = __builtin_amdgcn_mfma_f32_16x16x32_bf16(
                    af[kk][mo], U.s, acc[mo][nd], 0, 0, 0);
        }
    }

    // epilogue: C/D layout col=lane&15, row=(lane>>4)*4+reg (m89-verified)
    float* ob = out + (size_t)b * NO * NN + tile * 256 + w * 64 + ln;
    #pragma unroll
    for (int mo = 0; mo < 4; ++mo) {
        #pragma unroll
        for (int nd = 0; nd < 4; ++nd) {
            f32x4 v = acc[mo][nd];
            ob[(size_t)(mo * 16 + grp * 4 + 0) * NN + nd * 16] = v[0] + bias4[mo].x;
            ob[(size_t)(mo * 16 + grp * 4 + 1) * NN + nd * 16] = v[1] + bias4[mo].y;
            ob[(size_t)(mo * 16 + grp * 4 + 2) * NN + nd * 16] = v[2] + bias4[mo].z;
            ob[(size_t)(mo * 16 + grp * 4 + 3) * NN + nd * 16] = v[3] + bias4[mo].w;
        }
    }
}

extern "C" void kernel_launch(void* const* d_in, const int* in_sizes, int n_in,
                              void* d_out, int out_size, void* d_ws, size_t ws_size,
                              hipStream_t stream) {
    const float* x     = (const float*)d_in[0];
    const float* gamma = (const float*)d_in[1];
    const float* beta  = (const float*)d_in[2];
    const float* Wt    = (const float*)d_in[3];
    const float* bias  = (const float*)d_in[4];
    float* out = (float*)d_out;
    float* ws  = (float*)d_ws;

    float* part = ws;                                    // 1024 floats
    float* pp   = ws + 1024;                             // 4096 floats
    unsigned short* WtB = (unsigned short*)(ws + 5120);  // 4096 ushorts

    k_stats<<<dim3(NB * NC), dim3(256), 0, stream>>>(x, part, Wt, WtB);
    k_cost<<<dim3(NB * NC), dim3(256), 0, stream>>>(x, part, gamma, beta, pp);
    k_out<<<dim3(NB * NC), dim3(256), 0, stream>>>(x, WtB, bias, pp, out);
}